// Round 6
// baseline (149.619 us; speedup 1.0000x reference)
//
#include <hip/hip_runtime.h>
#include <math.h>

#define DIM 128
#define N_TOT 200
#define HALF_ROWS 100
#define FDIM 384
#define NT 16
#define NTILES 7        // 7*16 = 112 >= 100 rows per half
#define KSTEPS 12
#define THREADS 512     // 8 waves; wave w owns d-rows [16w, 16w+16)
#define NUNITS 2048     // (b, half)

typedef __attribute__((ext_vector_type(8))) short short8;
typedef __attribute__((ext_vector_type(4))) float f32x4;

__device__ __forceinline__ unsigned short f2bf(float f) {
    unsigned int u = __float_as_uint(f);
    u += 0x7fffu + ((u >> 16) & 1u);          // RNE
    return (unsigned short)(u >> 16);
}
__device__ __forceinline__ float fast_tanh(float x) {
    return 1.f - 2.f / (__expf(2.f * x) + 1.f);
}

// d_ws: Pws[2048][128] float, then Lws[2048] float
__global__ __launch_bounds__(THREADS, 3)
void acv_phase1(const int* __restrict__ xs_xt,        // [B][N][2]
                const int* __restrict__ path_idx,     // [B][N]
                const float* __restrict__ value_vocab,
                const float* __restrict__ path_vocab,
                const float* __restrict__ W,          // [128][384]
                const float* __restrict__ att_vec,
                float* __restrict__ Pws,
                float* __restrict__ Lws)
{
    // ctx tiles in MFMA-fragment granule order, bf16, double-buffered.
    // granule(ks,row,g): 16B at ks*1024 + ((row*64 + g*16) ^ ((ks&1)<<6))
    __shared__ __align__(16) char ctx[2][NT * FDIM * 2];   // 2 x 12 KB
    __shared__ float spart[2][NT][8];
    __shared__ int   idx0[HALF_ROWS], idx1[HALF_ROWS], idxp[HALF_ROWS];

    const int unit = blockIdx.x;
    const int b    = unit >> 1;
    const int h    = unit & 1;
    const int tid  = threadIdx.x;
    const int wave = tid >> 6;
    const int lane = tid & 63;
    const int c    = lane & 15;       // MFMA row/col-within-16
    const int g    = lane >> 4;       // k-slot

    // ---- per-block index preload (this half's 100 rows) ----
    const int* xs_b = xs_xt + b * (N_TOT * 2) + h * (HALF_ROWS * 2);
    const int* p_b  = path_idx + b * N_TOT + h * HALF_ROWS;
    for (int n = tid; n < HALF_ROWS; n += THREADS) {
        idx0[n] = xs_b[2 * n];
        idx1[n] = xs_b[2 * n + 1];
        idxp[n] = p_b[n];
    }
    __syncthreads();

    // ---- staging: 1536 dwordx4 units per tile, 3 per thread, coalesced ----
    auto stage_issue = [&](int t, float4* pf) {
        const int t0 = t * NT;
        #pragma unroll
        for (int p = 0; p < 3; ++p) {
            int u   = tid + THREADS * p;      // 0..1535
            int s   = u >> 5;                 // segment id 0..47
            int off = u & 31;                 // dwordx4 within 512B segment
            int seg = s >> 4;                 // 0: xs0, 1: path, 2: xs1
            int nl  = s & 15;                 // local row in tile
            int n   = t0 + nl; if (n > HALF_ROWS - 1) n = HALF_ROWS - 1;
            const float* src;
            if      (seg == 0) src = value_vocab + (size_t)idx0[n] * DIM;
            else if (seg == 1) src = path_vocab  + (size_t)idxp[n] * DIM;
            else               src = value_vocab + (size_t)idx1[n] * DIM;
            pf[p] = *(const float4*)(src + off * 4);
        }
    };
    auto stage_write = [&](char* base, const float4* pf) {
        #pragma unroll
        for (int p = 0; p < 3; ++p) {
            int u   = tid + THREADS * p;
            int s   = u >> 5, off = u & 31;
            int seg = s >> 4, nl  = s & 15;
            int f   = seg * 128 + off * 4;
            int ks  = f >> 5, gg = (f >> 3) & 3, hh = (f >> 2) & 1;
            int byte = ks * 1024 + ((nl * 64 + gg * 16) ^ ((ks & 1) << 6)) + hh * 8;
            float4 v = pf[p];
            unsigned int lo = ((unsigned)f2bf(v.y) << 16) | (unsigned)f2bf(v.x);
            unsigned int hi = ((unsigned)f2bf(v.w) << 16) | (unsigned)f2bf(v.z);
            *(uint2*)(base + byte) = make_uint2(lo, hi);
        }
    };

    float4 pfA[3];

    // ---- prologue ----
    stage_issue(0, pfA);
    short8 wfrag[KSTEPS];     // W fragments into registers, overlapping pfA latency
    {
        const float* wrow = W + (size_t)(16 * wave + c) * FDIM + 8 * g;
        #pragma unroll
        for (int ks = 0; ks < KSTEPS; ++ks) {
            float4 q0 = *(const float4*)(wrow + 32 * ks);
            float4 q1 = *(const float4*)(wrow + 32 * ks + 4);
            short8 wv;
            wv[0] = (short)f2bf(q0.x); wv[1] = (short)f2bf(q0.y);
            wv[2] = (short)f2bf(q0.z); wv[3] = (short)f2bf(q0.w);
            wv[4] = (short)f2bf(q1.x); wv[5] = (short)f2bf(q1.y);
            wv[6] = (short)f2bf(q1.z); wv[7] = (short)f2bf(q1.w);
            wfrag[ks] = wv;
        }
    }
    const float a_val = att_vec[16 * wave + c];

    stage_write(ctx[0], pfA);     // waits pfA (tile 0)
    stage_issue(1, pfA);          // tile 1 in flight
    __syncthreads();              // tile 0 visible

    float P = 0.f, L = 0.f;
    float comb[4];

    auto do_tile = [&](int t) {
        const char* cb = ctx[t & 1];
        f32x4 acc = {0.f, 0.f, 0.f, 0.f};
        #pragma unroll
        for (int ks = 0; ks < KSTEPS; ++ks) {
            short8 af = *(const short8*)(cb + ks * 1024 + ((c * 64 + g * 16) ^ ((ks & 1) << 6)));
            acc = __builtin_amdgcn_mfma_f32_16x16x32_bf16(af, wfrag[ks], acc, 0, 0, 0);
        }
        float sp[4];
        #pragma unroll
        for (int r = 0; r < 4; ++r) {
            comb[r] = fast_tanh(acc[r]);
            sp[r]   = comb[r] * a_val;
        }
        #pragma unroll
        for (int r = 0; r < 4; ++r) {          // reduce over the 16 cols (c)
            sp[r] += __shfl_xor(sp[r], 1, 64);
            sp[r] += __shfl_xor(sp[r], 2, 64);
            sp[r] += __shfl_xor(sp[r], 4, 64);
            sp[r] += __shfl_xor(sp[r], 8, 64);
        }
        if (c == 0) {
            #pragma unroll
            for (int r = 0; r < 4; ++r) spart[t & 1][4 * g + r][wave] = sp[r];
        }
    };
    auto finish_tile = [&](int t) {
        #pragma unroll
        for (int r = 0; r < 4; ++r) {
            int n = 4 * g + r;
            float4 s0 = *(const float4*)&spart[t & 1][n][0];
            float4 s1 = *(const float4*)&spart[t & 1][n][4];
            float s = ((s0.x + s0.y) + (s0.z + s0.w)) + ((s1.x + s1.y) + (s1.z + s1.w));
            float e = (t * NT + n < HALF_ROWS) ? __expf(s) : 0.f;   // |s|<=~5
            L += e;
            P = fmaf(e, comb[r], P);
        }
    };

    #pragma unroll 1
    for (int t = 0; t < NTILES; ++t) {
        do_tile(t);
        if (t + 1 < NTILES) {
            stage_write(ctx[(t + 1) & 1], pfA);     // tile t+1 (in flight since t-1)
            if (t + 2 < NTILES) stage_issue(t + 2, pfA);
        }
        __syncthreads();   // spart[t&1] ready AND ctx[(t+1)&1] visible
        finish_tile(t);
    }

    // ---- reduce over g; write half partials ----
    P += __shfl_xor(P, 16, 64);
    P += __shfl_xor(P, 32, 64);
    L += __shfl_xor(L, 16, 64);
    L += __shfl_xor(L, 32, 64);
    if (g == 0) Pws[(size_t)unit * DIM + 16 * wave + c] = P;
    if (tid == 0) Lws[unit] = L;
}

__global__ __launch_bounds__(128, 8)
void acv_phase2(const float* __restrict__ Pws, const float* __restrict__ Lws,
                const float* __restrict__ dense_w, const float* __restrict__ dense_b,
                float* __restrict__ out)
{
    __shared__ float code_s[DIM];
    const int b = blockIdx.x, tid = threadIdx.x;
    float L = Lws[2 * b] + Lws[2 * b + 1];
    code_s[tid] = (Pws[(size_t)(2 * b) * DIM + tid] + Pws[(size_t)(2 * b + 1) * DIM + tid]) / L;
    __syncthreads();
    float a = dense_b[tid];
    #pragma unroll 8
    for (int d = 0; d < DIM; ++d) a = fmaf(code_s[d], dense_w[d * DIM + tid], a);
    out[(size_t)b * DIM + tid] = 1.f / (1.f + __expf(-a));
}

extern "C" void kernel_launch(void* const* d_in, const int* in_sizes, int n_in,
                              void* d_out, int out_size, void* d_ws, size_t ws_size,
                              hipStream_t stream) {
    const int*   xs_xt       = (const int*)d_in[0];
    const int*   path_idx    = (const int*)d_in[1];
    const float* value_vocab = (const float*)d_in[2];
    const float* path_vocab  = (const float*)d_in[3];
    const float* W           = (const float*)d_in[4];
    const float* att_vec     = (const float*)d_in[5];
    const float* dense_w     = (const float*)d_in[6];
    const float* dense_b     = (const float*)d_in[7];
    float*       out         = (float*)d_out;

    float* Pws = (float*)d_ws;               // 2048*128 floats
    float* Lws = Pws + NUNITS * DIM;         // 2048 floats

    acv_phase1<<<NUNITS, THREADS, 0, stream>>>(xs_xt, path_idx, value_vocab, path_vocab,
                                               W, att_vec, Pws, Lws);
    acv_phase2<<<1024, 128, 0, stream>>>(Pws, Lws, dense_w, dense_b, out);
}

// Round 7
// 111.393 us; speedup vs baseline: 1.3432x; 1.3432x over previous
//
#include <hip/hip_runtime.h>
#include <hip/hip_bf16.h>
#include <math.h>

#define DIM 128
#define N_TOT 200
#define FDIM 384
#define NT 32
#define NTILES 7        // 7*32 = 224 >= 200 (tail rows clamp, masked in softmax)
#define KSTEPS 12
#define THREADS 512     // 8 waves; wave w owns d-rows [16w, 16w+16)

typedef __attribute__((ext_vector_type(8))) short short8;
typedef __attribute__((ext_vector_type(4))) float f32x4;

__device__ __forceinline__ unsigned pk2(float x, float y) {
    // v_cvt_pk_bf16_f32 via compiler (RNE)
    union { __hip_bfloat162 h; unsigned u; } cv;
    cv.h = __float22bfloat162_rn(make_float2(x, y));
    return cv.u;
}
__device__ __forceinline__ float fast_tanh(float x) {
    return 1.f - 2.f / (__expf(2.f * x) + 1.f);
}

__global__ __launch_bounds__(THREADS, 3)
void acv_kernel(const int* __restrict__ xs_xt,        // [B][N][2]
                const int* __restrict__ path_idx,     // [B][N]
                const float* __restrict__ value_vocab,
                const float* __restrict__ path_vocab,
                const float* __restrict__ W,          // [128][384]
                const float* __restrict__ att_vec,
                const float* __restrict__ dense_w,    // [128][128]
                const float* __restrict__ dense_b,
                float* __restrict__ out)              // [B][128]
{
    // ctx tiles in MFMA-fragment granule order, bf16, double-buffered.
    // granule(ks,row,gg): 16B at ks*2048 + ((row*64 + gg*16) ^ ((ks&1)<<6))
    __shared__ __align__(16) char ctx[2][NT * FDIM * 2];   // 2 x 24 KB
    __shared__ float spart[2][NT][8];
    __shared__ int   idx0[N_TOT], idx1[N_TOT], idxp[N_TOT];
    __shared__ float code_s[DIM];
    __shared__ float red[4][DIM];

    const int b    = blockIdx.x;
    const int tid  = threadIdx.x;
    const int wave = tid >> 6;
    const int lane = tid & 63;
    const int c    = lane & 15;       // MFMA row/col-within-16
    const int g    = lane >> 4;       // k-slot

    // ---- per-block index preload ----
    const int* xs_b = xs_xt + b * (N_TOT * 2);
    const int* p_b  = path_idx + b * N_TOT;
    for (int n = tid; n < N_TOT; n += THREADS) {
        idx0[n] = xs_b[2 * n];
        idx1[n] = xs_b[2 * n + 1];
        idxp[n] = p_b[n];
    }
    __syncthreads();

    // ---- staging: 3072 dwordx4 units per tile, 6 per thread, coalesced ----
    auto stage_issue = [&](int t, float4* pf) {
        const int t0 = t * NT;
        #pragma unroll
        for (int p = 0; p < 6; ++p) {
            int u   = tid + THREADS * p;      // 0..3071
            int s   = u >> 5;                 // segment-row id 0..95
            int off = u & 31;                 // dwordx4 within 512B row
            int seg = s >> 5;                 // 0: xs0, 1: path, 2: xs1
            int nl  = s & 31;                 // local row in tile
            int n   = t0 + nl; if (n > N_TOT - 1) n = N_TOT - 1;
            const float* src;
            if      (seg == 0) src = value_vocab + (size_t)idx0[n] * DIM;
            else if (seg == 1) src = path_vocab  + (size_t)idxp[n] * DIM;
            else               src = value_vocab + (size_t)idx1[n] * DIM;
            pf[p] = *(const float4*)(src + off * 4);
        }
    };
    auto stage_write = [&](char* base, const float4* pf) {
        #pragma unroll
        for (int p = 0; p < 6; ++p) {
            int u   = tid + THREADS * p;
            int s   = u >> 5, off = u & 31;
            int nl  = s & 31;
            int f   = (s >> 5) * 128 + off * 4;
            int ks  = f >> 5, gg = (f >> 3) & 3, hh = (f >> 2) & 1;
            int byte = ks * 2048 + ((nl * 64 + gg * 16) ^ ((ks & 1) << 6)) + hh * 8;
            float4 v = pf[p];
            *(uint2*)(base + byte) = make_uint2(pk2(v.x, v.y), pk2(v.z, v.w));
        }
    };

    float4 pfA[6];

    // ---- prologue ----
    stage_issue(0, pfA);
    short8 wfrag[KSTEPS];     // W fragments into registers, overlapping pfA latency
    {
        const float* wrow = W + (size_t)(16 * wave + c) * FDIM + 8 * g;
        #pragma unroll
        for (int ks = 0; ks < KSTEPS; ++ks) {
            float4 q0 = *(const float4*)(wrow + 32 * ks);
            float4 q1 = *(const float4*)(wrow + 32 * ks + 4);
            union { short8 s8; unsigned u4[4]; } cv;
            cv.u4[0] = pk2(q0.x, q0.y); cv.u4[1] = pk2(q0.z, q0.w);
            cv.u4[2] = pk2(q1.x, q1.y); cv.u4[3] = pk2(q1.z, q1.w);
            wfrag[ks] = cv.s8;
        }
    }
    const float a_val = att_vec[16 * wave + c];

    stage_write(ctx[0], pfA);     // waits pfA (tile 0)
    stage_issue(1, pfA);          // tile 1 in flight
    __syncthreads();              // tile 0 visible

    float P = 0.f, L = 0.f;
    float comb0[4], comb1[4];

    auto do_tile = [&](int t) {
        const char* cb = ctx[t & 1];
        f32x4 acc0 = {0.f, 0.f, 0.f, 0.f};
        f32x4 acc1 = {0.f, 0.f, 0.f, 0.f};
        #pragma unroll
        for (int ks = 0; ks < KSTEPS; ++ks) {
            int sw = (ks & 1) << 6;
            short8 a0 = *(const short8*)(cb + ks * 2048 + ((c * 64 + g * 16) ^ sw));
            short8 a1 = *(const short8*)(cb + ks * 2048 + 1024 + ((c * 64 + g * 16) ^ sw));
            acc0 = __builtin_amdgcn_mfma_f32_16x16x32_bf16(a0, wfrag[ks], acc0, 0, 0, 0);
            acc1 = __builtin_amdgcn_mfma_f32_16x16x32_bf16(a1, wfrag[ks], acc1, 0, 0, 0);
        }
        float sp0[4], sp1[4];
        #pragma unroll
        for (int r = 0; r < 4; ++r) {
            comb0[r] = fast_tanh(acc0[r]);  sp0[r] = comb0[r] * a_val;
            comb1[r] = fast_tanh(acc1[r]);  sp1[r] = comb1[r] * a_val;
        }
        #pragma unroll
        for (int r = 0; r < 4; ++r) {          // reduce over the 16 cols (c)
            sp0[r] += __shfl_xor(sp0[r], 1, 64);
            sp0[r] += __shfl_xor(sp0[r], 2, 64);
            sp0[r] += __shfl_xor(sp0[r], 4, 64);
            sp0[r] += __shfl_xor(sp0[r], 8, 64);
            sp1[r] += __shfl_xor(sp1[r], 1, 64);
            sp1[r] += __shfl_xor(sp1[r], 2, 64);
            sp1[r] += __shfl_xor(sp1[r], 4, 64);
            sp1[r] += __shfl_xor(sp1[r], 8, 64);
        }
        if (c == 0) {
            #pragma unroll
            for (int r = 0; r < 4; ++r) {
                spart[t & 1][4 * g + r][wave]      = sp0[r];
                spart[t & 1][16 + 4 * g + r][wave] = sp1[r];
            }
        }
    };
    auto finish_tile = [&](int t) {
        #pragma unroll
        for (int r = 0; r < 4; ++r) {
            int n = 4 * g + r;
            float4 s0 = *(const float4*)&spart[t & 1][n][0];
            float4 s1 = *(const float4*)&spart[t & 1][n][4];
            float s = ((s0.x + s0.y) + (s0.z + s0.w)) + ((s1.x + s1.y) + (s1.z + s1.w));
            float e = (t * NT + n < N_TOT) ? __expf(s) : 0.f;   // |s|<=~5: no max-sub
            L += e;
            P = fmaf(e, comb0[r], P);
        }
        #pragma unroll
        for (int r = 0; r < 4; ++r) {
            int n = 16 + 4 * g + r;
            float4 s0 = *(const float4*)&spart[t & 1][n][0];
            float4 s1 = *(const float4*)&spart[t & 1][n][4];
            float s = ((s0.x + s0.y) + (s0.z + s0.w)) + ((s1.x + s1.y) + (s1.z + s1.w));
            float e = (t * NT + n < N_TOT) ? __expf(s) : 0.f;
            L += e;
            P = fmaf(e, comb1[r], P);
        }
    };

    #pragma unroll 1
    for (int t = 0; t < NTILES; ++t) {
        // write tile t+1 (loads issued 2 iters ago), then issue t+2 BEFORE compute
        if (t + 1 < NTILES) {
            stage_write(ctx[(t + 1) & 1], pfA);
            if (t + 2 < NTILES) stage_issue(t + 2, pfA);
        }
        do_tile(t);
        __syncthreads();   // spart[t&1] ready AND ctx[(t+1)&1] visible
        finish_tile(t);
    }

    // ---- reduce over g; code = P/L ----
    P += __shfl_xor(P, 16, 64);
    P += __shfl_xor(P, 32, 64);
    L += __shfl_xor(L, 16, 64);
    L += __shfl_xor(L, 32, 64);
    if (g == 0) code_s[16 * wave + c] = P / L;
    __syncthreads();

    // ---- dense + sigmoid ----
    const int o   = tid & 127;
    const int seg = tid >> 7;
    float partial = 0.f;
    #pragma unroll 8
    for (int d = 32 * seg; d < 32 * seg + 32; ++d)
        partial = fmaf(code_s[d], dense_w[d * DIM + o], partial);
    red[seg][o] = partial;
    __syncthreads();
    if (tid < DIM) {
        float a2 = dense_b[tid] + ((red[0][tid] + red[1][tid]) + (red[2][tid] + red[3][tid]));
        out[(size_t)b * DIM + tid] = 1.f / (1.f + __expf(-a2));
    }
}

extern "C" void kernel_launch(void* const* d_in, const int* in_sizes, int n_in,
                              void* d_out, int out_size, void* d_ws, size_t ws_size,
                              hipStream_t stream) {
    const int*   xs_xt       = (const int*)d_in[0];
    const int*   path_idx    = (const int*)d_in[1];
    const float* value_vocab = (const float*)d_in[2];
    const float* path_vocab  = (const float*)d_in[3];
    const float* W           = (const float*)d_in[4];
    const float* att_vec     = (const float*)d_in[5];
    const float* dense_w     = (const float*)d_in[6];
    const float* dense_b     = (const float*)d_in[7];
    float*       out         = (float*)d_out;

    acv_kernel<<<1024, THREADS, 0, stream>>>(xs_xt, path_idx, value_vocab, path_vocab,
                                             W, att_vec, dense_w, dense_b, out);
}

// Round 8
// 82.976 us; speedup vs baseline: 1.8032x; 1.3425x over previous
//
#include <hip/hip_runtime.h>
#include <hip/hip_bf16.h>
#include <math.h>

#define DIM 128
#define N_TOT 200
#define FDIM 384
#define NT 32
#define NTILES 7        // 7*32 = 224 >= 200 (tail masked)
#define KSTEPS 12
#define THREADS 512     // 8 waves; wave w owns d-rows [16w, 16w+16)
#define NPAD 224

typedef __attribute__((ext_vector_type(8))) short short8;
typedef __attribute__((ext_vector_type(4))) float f32x4;

__device__ __forceinline__ unsigned pk2(float x, float y) {
    union { __hip_bfloat162 h; unsigned u; } cv;
    cv.h = __float22bfloat162_rn(make_float2(x, y));   // v_cvt_pk_bf16_f32
    return cv.u;
}
__device__ __forceinline__ float fast_tanh(float x) {
    return 1.f - 2.f / (__expf(2.f * x) + 1.f);
}

// ---- pre-kernel: W -> bf16 MFMA B-fragments in d_ws (96 KB, fragment order) ----
// frag(ds,ks,lane) 8 shorts: W[16ds+(lane&15)][32ks+8(lane>>4)+e], e=0..7
__global__ __launch_bounds__(256, 4)
void prep_w(const float* __restrict__ W, unsigned* __restrict__ wsB) {
    int o = blockIdx.x * 256 + threadIdx.x;   // 0..24575 (uint granularity)
    int q = o & 3, lane = (o >> 2) & 63, t = o >> 8;
    int ks = t % 12, ds = t / 12;
    int d = 16 * ds + (lane & 15);
    int f = 32 * ks + 8 * (lane >> 4) + 2 * q;
    wsB[o] = pk2(W[d * FDIM + f], W[d * FDIM + f + 1]);
}

__global__ __launch_bounds__(THREADS, 4)
void acv_kernel(const int* __restrict__ xs_xt,        // [B][N][2]
                const int* __restrict__ path_idx,     // [B][N]
                const float* __restrict__ value_vocab,
                const float* __restrict__ path_vocab,
                const unsigned* __restrict__ wsB,     // W bf16 fragments
                const float* __restrict__ att_vec,
                const float* __restrict__ dense_w,    // [128][128]
                const float* __restrict__ dense_b,
                float* __restrict__ out)              // [B][128]
{
    // ctx tiles in MFMA-fragment granule order, bf16, double-buffered.
    // granule(ks,row,gg): 16B at ks*2048 + ((row*64 + gg*16) ^ ((ks&1)<<6))
    __shared__ __align__(16) char ctx[2][NT * FDIM * 2];   // 2 x 24 KB
    __shared__ float spart[2][8][32];     // [buf][wave][row]
    __shared__ const char* rowp[3 * NPAD];// precomputed gather-row base pointers
    __shared__ float code_s[DIM];
    __shared__ float red[4][DIM];

    const int b    = blockIdx.x;
    const int tid  = threadIdx.x;
    const int wave = tid >> 6;
    const int lane = tid & 63;
    const int c    = lane & 15;       // MFMA col-within-16
    const int g    = lane >> 4;       // k-slot / row-group

    // ---- per-block: precompute gather row pointers (padded to 224) ----
    const int* xs_b = xs_xt + b * (N_TOT * 2);
    const int* p_b  = path_idx + b * N_TOT;
    for (int i = tid; i < 3 * NPAD; i += THREADS) {
        int seg = i / NPAD, n = i - seg * NPAD;
        int m = n < N_TOT ? n : N_TOT - 1;
        const char* base;
        if      (seg == 0) base = (const char*)(value_vocab + (size_t)xs_b[2 * m]     * DIM);
        else if (seg == 1) base = (const char*)(path_vocab  + (size_t)p_b[m]          * DIM);
        else               base = (const char*)(value_vocab + (size_t)xs_b[2 * m + 1] * DIM);
        rowp[i] = base;
    }
    __syncthreads();

    // ---- staging invariants (per thread, computed once) ----
    int ridx[6], boff[6], ldsb[6];
    #pragma unroll
    for (int p = 0; p < 6; ++p) {
        int u   = tid + THREADS * p;      // 0..3071
        int s   = u >> 5, off = u & 31;
        int seg = s >> 5, nl  = s & 31;
        ridx[p] = seg * NPAD + nl;
        boff[p] = off * 16;
        int f  = seg * 128 + off * 4;
        int ks = f >> 5, gg = (f >> 3) & 3, hh = (f >> 2) & 1;
        ldsb[p] = ks * 2048 + ((nl * 64 + gg * 16) ^ ((ks & 1) << 6)) + hh * 8;
    }

    auto stage_issue = [&](int t, float4* pf) {
        #pragma unroll
        for (int p = 0; p < 6; ++p) {
            const char* rp = rowp[ridx[p] + t * NT];
            pf[p] = *(const float4*)(rp + boff[p]);
        }
    };
    auto stage_write = [&](char* base, const float4* pf) {
        #pragma unroll
        for (int p = 0; p < 6; ++p) {
            float4 v = pf[p];
            *(uint2*)(base + ldsb[p]) = make_uint2(pk2(v.x, v.y), pk2(v.z, v.w));
        }
    };

    float4 pfA[6];

    // ---- prologue ----
    stage_issue(0, pfA);
    const float a_val = att_vec[16 * wave + c];
    stage_write(ctx[0], pfA);     // waits pfA (tile 0)
    stage_issue(1, pfA);          // tile 1 in flight
    __syncthreads();              // tile 0 visible

    float P = 0.f, L = 0.f;
    float comb0[4], comb1[4];
    const char* wb = (const char*)wsB + wave * (KSTEPS * 1024) + lane * 16;
    const int   ab = c * 64 + g * 16;

    auto do_tile = [&](int t) {
        const char* cb = ctx[t & 1];
        f32x4 acc0 = {0.f, 0.f, 0.f, 0.f};
        f32x4 acc1 = {0.f, 0.f, 0.f, 0.f};
        #pragma unroll
        for (int ks = 0; ks < KSTEPS; ++ks) {
            int sw = (ks & 1) << 6;
            short8 bfr = *(const short8*)(wb + ks * 1024);
            short8 a0  = *(const short8*)(cb + ks * 2048 + (ab ^ sw));
            short8 a1  = *(const short8*)(cb + ks * 2048 + 1024 + (ab ^ sw));
            acc0 = __builtin_amdgcn_mfma_f32_16x16x32_bf16(a0, bfr, acc0, 0, 0, 0);
            acc1 = __builtin_amdgcn_mfma_f32_16x16x32_bf16(a1, bfr, acc1, 0, 0, 0);
        }
        float sp0[4], sp1[4];
        #pragma unroll
        for (int r = 0; r < 4; ++r) {
            comb0[r] = fast_tanh(acc0[r]);  sp0[r] = comb0[r] * a_val;
            comb1[r] = fast_tanh(acc1[r]);  sp1[r] = comb1[r] * a_val;
        }
        #pragma unroll
        for (int r = 0; r < 4; ++r) {          // reduce over the 16 cols (c)
            sp0[r] += __shfl_xor(sp0[r], 1, 64);
            sp0[r] += __shfl_xor(sp0[r], 2, 64);
            sp0[r] += __shfl_xor(sp0[r], 4, 64);
            sp0[r] += __shfl_xor(sp0[r], 8, 64);
            sp1[r] += __shfl_xor(sp1[r], 1, 64);
            sp1[r] += __shfl_xor(sp1[r], 2, 64);
            sp1[r] += __shfl_xor(sp1[r], 4, 64);
            sp1[r] += __shfl_xor(sp1[r], 8, 64);
        }
        if (c == 0) {
            #pragma unroll
            for (int r = 0; r < 4; ++r) {
                spart[t & 1][wave][4 * g + r]      = sp0[r];
                spart[t & 1][wave][16 + 4 * g + r] = sp1[r];
            }
        }
    };
    auto finish_tile = [&](int t) {
        // each lane finishes one row (lane&31), distributes via shfl
        const int n0 = lane & 31;
        float ssum = 0.f;
        #pragma unroll
        for (int w = 0; w < 8; ++w) ssum += spart[t & 1][w][n0];
        float e_my = (t * NT + n0 < N_TOT) ? __expf(ssum) : 0.f;   // |s|<=~5
        #pragma unroll
        for (int r = 0; r < 4; ++r) {
            float e0 = __shfl(e_my, 4 * g + r, 64);
            L += e0;  P = fmaf(e0, comb0[r], P);
            float e1 = __shfl(e_my, 16 + 4 * g + r, 64);
            L += e1;  P = fmaf(e1, comb1[r], P);
        }
    };

    #pragma unroll 1
    for (int t = 0; t < NTILES; ++t) {
        if (t + 1 < NTILES) {
            stage_write(ctx[(t + 1) & 1], pfA);     // tile t+1 (issued at t-1)
            if (t + 2 < NTILES) stage_issue(t + 2, pfA);
        }
        do_tile(t);
        __syncthreads();   // spart[t&1] ready AND ctx[(t+1)&1] visible
        finish_tile(t);
    }

    // ---- reduce over g; code = P/L ----
    P += __shfl_xor(P, 16, 64);
    P += __shfl_xor(P, 32, 64);
    L += __shfl_xor(L, 16, 64);
    L += __shfl_xor(L, 32, 64);
    if (g == 0) code_s[16 * wave + c] = P / L;
    __syncthreads();

    // ---- dense + sigmoid ----
    const int o   = tid & 127;
    const int seg = tid >> 7;
    float partial = 0.f;
    #pragma unroll 8
    for (int d = 32 * seg; d < 32 * seg + 32; ++d)
        partial = fmaf(code_s[d], dense_w[d * DIM + o], partial);
    red[seg][o] = partial;
    __syncthreads();
    if (tid < DIM) {
        float a2 = dense_b[tid] + ((red[0][tid] + red[1][tid]) + (red[2][tid] + red[3][tid]));
        out[(size_t)b * DIM + tid] = 1.f / (1.f + __expf(-a2));
    }
}

extern "C" void kernel_launch(void* const* d_in, const int* in_sizes, int n_in,
                              void* d_out, int out_size, void* d_ws, size_t ws_size,
                              hipStream_t stream) {
    const int*   xs_xt       = (const int*)d_in[0];
    const int*   path_idx    = (const int*)d_in[1];
    const float* value_vocab = (const float*)d_in[2];
    const float* path_vocab  = (const float*)d_in[3];
    const float* W           = (const float*)d_in[4];
    const float* att_vec     = (const float*)d_in[5];
    const float* dense_w     = (const float*)d_in[6];
    const float* dense_b     = (const float*)d_in[7];
    float*       out         = (float*)d_out;

    unsigned* wsB = (unsigned*)d_ws;    // 24576 uints = 96 KB

    prep_w<<<96, 256, 0, stream>>>(W, wsB);
    acv_kernel<<<1024, THREADS, 0, stream>>>(xs_xt, path_idx, value_vocab, path_vocab,
                                             wsB, att_vec, dense_w, dense_b, out);
}

// Round 9
// 82.544 us; speedup vs baseline: 1.8126x; 1.0052x over previous
//
#include <hip/hip_runtime.h>
#include <hip/hip_bf16.h>
#include <math.h>

#define DIM 128
#define N_TOT 200
#define FDIM 384
#define NT 32
#define NTILES 7        // 7*32 = 224 >= 200 (tail masked)
#define KSTEPS 12
#define THREADS 512     // 8 waves; wave w owns d-rows [16w, 16w+16)
#define NPAD 256

typedef __attribute__((ext_vector_type(8))) short short8;
typedef __attribute__((ext_vector_type(4))) float f32x4;

__device__ __forceinline__ unsigned pk2(float x, float y) {
    union { __hip_bfloat162 h; unsigned u; } cv;
    cv.h = __float22bfloat162_rn(make_float2(x, y));   // v_cvt_pk_bf16_f32
    return cv.u;
}
__device__ __forceinline__ float fast_tanh(float x) {
    return 1.f - 2.f / (__expf(2.f * x) + 1.f);
}

// ---- pre-kernel: W -> bf16 MFMA B-fragments in d_ws (96 KB, fragment order) ----
// frag(ds,ks,lane) 8 shorts: W[16ds+(lane&15)][32ks+8(lane>>4)+e], e=0..7
__global__ __launch_bounds__(256, 4)
void prep_w(const float* __restrict__ W, unsigned* __restrict__ wsB) {
    int o = blockIdx.x * 256 + threadIdx.x;   // 0..24575 (uint granularity)
    int q = o & 3, lane = (o >> 2) & 63, t = o >> 8;
    int ks = t % 12, ds = t / 12;
    int d = 16 * ds + (lane & 15);
    int f = 32 * ks + 8 * (lane >> 4) + 2 * q;
    wsB[o] = pk2(W[d * FDIM + f], W[d * FDIM + f + 1]);
}

__global__ __launch_bounds__(THREADS, 4)
void acv_kernel(const int* __restrict__ xs_xt,        // [B][N][2]
                const int* __restrict__ path_idx,     // [B][N]
                const float* __restrict__ value_vocab,
                const float* __restrict__ path_vocab,
                const unsigned* __restrict__ wsB,     // W bf16 fragments
                const float* __restrict__ att_vec,
                const float* __restrict__ dense_w,    // [128][128]
                const float* __restrict__ dense_b,
                float* __restrict__ out)              // [B][128]
{
    // ctx tiles in MFMA-fragment granule order, bf16, double-buffered.
    // granule(ks,row,gg): 16B at ks*2048 + ((row*64 + gg*16) ^ ((ks&1)<<6))
    __shared__ __align__(16) char ctx[2][NT * FDIM * 2];   // 2 x 24 KB
    __shared__ float spart[2][8][32];     // [buf][wave][row]
    __shared__ const char* rowp[3 * NPAD];// precomputed gather-row base pointers
    __shared__ float code_s[DIM];
    __shared__ float red[4][DIM];

    const int b    = blockIdx.x;
    const int tid  = threadIdx.x;
    const int wave = tid >> 6;
    const int lane = tid & 63;
    const int c    = lane & 15;       // MFMA col-within-16
    const int g    = lane >> 4;       // k-slot / row-group

    // ---- per-block: precompute gather row pointers (padded to 256) ----
    const int* xs_b = xs_xt + b * (N_TOT * 2);
    const int* p_b  = path_idx + b * N_TOT;
    for (int i = tid; i < 3 * NPAD; i += THREADS) {
        int seg = i >> 8, n = i & (NPAD - 1);
        int m = n < N_TOT ? n : N_TOT - 1;
        const char* base;
        if      (seg == 0) base = (const char*)(value_vocab + (size_t)xs_b[2 * m]     * DIM);
        else if (seg == 1) base = (const char*)(path_vocab  + (size_t)p_b[m]          * DIM);
        else               base = (const char*)(value_vocab + (size_t)xs_b[2 * m + 1] * DIM);
        rowp[i] = base;
    }
    __syncthreads();

    // ---- staging invariants (per thread, computed once) ----
    int ridx[6], boff[6], ldsb[6];
    #pragma unroll
    for (int p = 0; p < 6; ++p) {
        int u   = tid + THREADS * p;      // 0..3071
        int s   = u >> 5, off = u & 31;
        int seg = s >> 5, nl  = s & 31;
        ridx[p] = seg * NPAD + nl;
        boff[p] = off * 16;
        int f  = seg * 128 + off * 4;
        int ks = f >> 5, gg = (f >> 3) & 3, hh = (f >> 2) & 1;
        ldsb[p] = ks * 2048 + ((nl * 64 + gg * 16) ^ ((ks & 1) << 6)) + hh * 8;
    }

    auto stage_issue = [&](int t, float4* pf) {
        #pragma unroll
        for (int p = 0; p < 6; ++p) {
            const char* rp = rowp[ridx[p] + t * NT];
            pf[p] = *(const float4*)(rp + boff[p]);
        }
    };
    auto stage_write = [&](char* base, const float4* pf) {
        #pragma unroll
        for (int p = 0; p < 6; ++p) {
            float4 v = pf[p];
            *(uint2*)(base + ldsb[p]) = make_uint2(pk2(v.x, v.y), pk2(v.z, v.w));
        }
    };

    float4 pfA[6];

    // ---- prologue ----
    stage_issue(0, pfA);
    const float a_val = att_vec[16 * wave + c];
    const char* wb = (const char*)wsB + wave * (KSTEPS * 1024) + lane * 16;
    short8 wfragE[6];                    // even-ks W fragments resident in regs
    #pragma unroll
    for (int j = 0; j < 6; ++j) wfragE[j] = *(const short8*)(wb + (2 * j) * 1024);

    stage_write(ctx[0], pfA);     // waits pfA (tile 0)
    stage_issue(1, pfA);          // tile 1 in flight
    __syncthreads();              // tile 0 visible

    float P = 0.f, L = 0.f;
    float comb0[4], comb1[4];
    const int ab = c * 64 + g * 16;

    auto do_tile = [&](int t) {
        const char* cb = ctx[t & 1];
        f32x4 ae0 = {0.f,0.f,0.f,0.f}, ae1 = {0.f,0.f,0.f,0.f};   // even-ks chains (reg W)
        f32x4 ao0 = {0.f,0.f,0.f,0.f}, ao1 = {0.f,0.f,0.f,0.f};   // odd-ks chains (L2 W)
        #pragma unroll
        for (int j = 0; j < 6; ++j) {
            const int kse = 2 * j, kso = 2 * j + 1;
            short8 bo  = *(const short8*)(wb + kso * 1024);          // L2 (half traffic)
            short8 a0e = *(const short8*)(cb + kse * 2048 + ab);            // sw=0 for even ks
            short8 a1e = *(const short8*)(cb + kse * 2048 + 1024 + ab);
            ae0 = __builtin_amdgcn_mfma_f32_16x16x32_bf16(a0e, wfragE[j], ae0, 0, 0, 0);
            ae1 = __builtin_amdgcn_mfma_f32_16x16x32_bf16(a1e, wfragE[j], ae1, 0, 0, 0);
            short8 a0o = *(const short8*)(cb + kso * 2048 + (ab ^ 64));     // sw=64 for odd ks
            short8 a1o = *(const short8*)(cb + kso * 2048 + 1024 + (ab ^ 64));
            ao0 = __builtin_amdgcn_mfma_f32_16x16x32_bf16(a0o, bo, ao0, 0, 0, 0);
            ao1 = __builtin_amdgcn_mfma_f32_16x16x32_bf16(a1o, bo, ao1, 0, 0, 0);
        }
        float sp0[4], sp1[4];
        #pragma unroll
        for (int r = 0; r < 4; ++r) {
            comb0[r] = fast_tanh(ae0[r] + ao0[r]);  sp0[r] = comb0[r] * a_val;
            comb1[r] = fast_tanh(ae1[r] + ao1[r]);  sp1[r] = comb1[r] * a_val;
        }
        #pragma unroll
        for (int r = 0; r < 4; ++r) {          // reduce over the 16 cols (c)
            sp0[r] += __shfl_xor(sp0[r], 1, 64);
            sp0[r] += __shfl_xor(sp0[r], 2, 64);
            sp0[r] += __shfl_xor(sp0[r], 4, 64);
            sp0[r] += __shfl_xor(sp0[r], 8, 64);
            sp1[r] += __shfl_xor(sp1[r], 1, 64);
            sp1[r] += __shfl_xor(sp1[r], 2, 64);
            sp1[r] += __shfl_xor(sp1[r], 4, 64);
            sp1[r] += __shfl_xor(sp1[r], 8, 64);
        }
        if (c == 0) {
            #pragma unroll
            for (int r = 0; r < 4; ++r) {
                spart[t & 1][wave][4 * g + r]      = sp0[r];
                spart[t & 1][wave][16 + 4 * g + r] = sp1[r];
            }
        }
    };
    auto finish_tile = [&](int t) {
        // each lane finishes one row (lane&31), distributes via shfl
        const int n0 = lane & 31;
        float ssum = 0.f;
        #pragma unroll
        for (int w = 0; w < 8; ++w) ssum += spart[t & 1][w][n0];
        float e_my = (t * NT + n0 < N_TOT) ? __expf(ssum) : 0.f;   // |s|<=~5
        #pragma unroll
        for (int r = 0; r < 4; ++r) {
            float e0 = __shfl(e_my, 4 * g + r, 64);
            L += e0;  P = fmaf(e0, comb0[r], P);
            float e1 = __shfl(e_my, 16 + 4 * g + r, 64);
            L += e1;  P = fmaf(e1, comb1[r], P);
        }
    };

    #pragma unroll 1
    for (int t = 0; t < NTILES; ++t) {
        if (t + 1 < NTILES) {
            stage_write(ctx[(t + 1) & 1], pfA);     // tile t+1 (issued at t-1)
            if (t + 2 < NTILES) stage_issue(t + 2, pfA);
        }
        do_tile(t);
        __syncthreads();   // spart[t&1] ready AND ctx[(t+1)&1] visible
        finish_tile(t);
    }

    // ---- reduce over g; code = P/L ----
    P += __shfl_xor(P, 16, 64);
    P += __shfl_xor(P, 32, 64);
    L += __shfl_xor(L, 16, 64);
    L += __shfl_xor(L, 32, 64);
    if (g == 0) code_s[16 * wave + c] = P / L;
    __syncthreads();

    // ---- dense + sigmoid ----
    const int o   = tid & 127;
    const int seg = tid >> 7;
    float partial = 0.f;
    #pragma unroll 8
    for (int d = 32 * seg; d < 32 * seg + 32; ++d)
        partial = fmaf(code_s[d], dense_w[d * DIM + o], partial);
    red[seg][o] = partial;
    __syncthreads();
    if (tid < DIM) {
        float a2 = dense_b[tid] + ((red[0][tid] + red[1][tid]) + (red[2][tid] + red[3][tid]));
        out[(size_t)b * DIM + tid] = 1.f / (1.f + __expf(-a2));
    }
}

extern "C" void kernel_launch(void* const* d_in, const int* in_sizes, int n_in,
                              void* d_out, int out_size, void* d_ws, size_t ws_size,
                              hipStream_t stream) {
    const int*   xs_xt       = (const int*)d_in[0];
    const int*   path_idx    = (const int*)d_in[1];
    const float* value_vocab = (const float*)d_in[2];
    const float* path_vocab  = (const float*)d_in[3];
    const float* W           = (const float*)d_in[4];
    const float* att_vec     = (const float*)d_in[5];
    const float* dense_w     = (const float*)d_in[6];
    const float* dense_b     = (const float*)d_in[7];
    float*       out         = (float*)d_out;

    unsigned* wsB = (unsigned*)d_ws;    // 24576 uints = 96 KB

    prep_w<<<96, 256, 0, stream>>>(W, wsB);
    acv_kernel<<<1024, THREADS, 0, stream>>>(xs_xt, path_idx, value_vocab, path_vocab,
                                             wsB, att_vec, dense_w, dense_b, out);
}

// Round 10
// 70.807 us; speedup vs baseline: 2.1130x; 1.1658x over previous
//
#include <hip/hip_runtime.h>
#include <hip/hip_bf16.h>
#include <math.h>

#define DIM 128
#define N_TOT 200
#define FDIM 384
#define NT 16
#define NTILES 13       // 13*16 = 208 >= 200 (tail masked)
#define KSTEPS 12
#define THREADS 256     // 4 waves; wave w owns d-rows [32w, 32w+32)
#define NPAD 256

typedef __attribute__((ext_vector_type(8))) short short8;
typedef __attribute__((ext_vector_type(4))) float f32x4;

__device__ __forceinline__ unsigned pk2(float x, float y) {
    union { __hip_bfloat162 h; unsigned u; } cv;
    cv.h = __float22bfloat162_rn(make_float2(x, y));   // v_cvt_pk_bf16_f32
    return cv.u;
}
__device__ __forceinline__ float fast_tanh(float x) {
    return 1.f - 2.f / (__expf(2.f * x) + 1.f);
}
// 16-lane sum via DPP (VALU pipe, no LDS): quad_perm[1,0,3,2], [2,3,0,1],
// row_half_mirror, row_mirror. Result replicated across the 16-lane row.
__device__ __forceinline__ float dpp_red16(float x) {
    int v;
    v = __builtin_amdgcn_update_dpp(0, __builtin_bit_cast(int, x), 0xB1, 0xF, 0xF, false);
    x += __builtin_bit_cast(float, v);
    v = __builtin_amdgcn_update_dpp(0, __builtin_bit_cast(int, x), 0x4E, 0xF, 0xF, false);
    x += __builtin_bit_cast(float, v);
    v = __builtin_amdgcn_update_dpp(0, __builtin_bit_cast(int, x), 0x141, 0xF, 0xF, false);
    x += __builtin_bit_cast(float, v);
    v = __builtin_amdgcn_update_dpp(0, __builtin_bit_cast(int, x), 0x140, 0xF, 0xF, false);
    x += __builtin_bit_cast(float, v);
    return x;
}

// ---- pre-kernel: W -> bf16 MFMA B-fragments in d_ws (96 KB, fragment order) ----
// frag(ds,ks,lane) 8 shorts: W[16ds+(lane&15)][32ks+8(lane>>4)+e], e=0..7
__global__ __launch_bounds__(256, 4)
void prep_w(const float* __restrict__ W, unsigned* __restrict__ wsB) {
    int o = blockIdx.x * 256 + threadIdx.x;   // 0..24575 (uint granularity)
    int q = o & 3, lane = (o >> 2) & 63, t = o >> 8;
    int ks = t % 12, ds = t / 12;
    int d = 16 * ds + (lane & 15);
    int f = 32 * ks + 8 * (lane >> 4) + 2 * q;
    wsB[o] = pk2(W[d * FDIM + f], W[d * FDIM + f + 1]);
}

__global__ __launch_bounds__(THREADS, 3)
void acv_kernel(const int* __restrict__ xs_xt,        // [B][N][2]
                const int* __restrict__ path_idx,     // [B][N]
                const float* __restrict__ value_vocab,
                const float* __restrict__ path_vocab,
                const unsigned* __restrict__ wsB,     // W bf16 fragments
                const float* __restrict__ att_vec,
                const float* __restrict__ dense_w,    // [128][128]
                const float* __restrict__ dense_b,
                float* __restrict__ out)              // [B][128]
{
    // ctx tiles in MFMA-fragment granule order, bf16, double-buffered.
    // granule(ks,row,gg): 16B at ks*1024 + ((row*64 + gg*16) ^ ((ks&1)<<6))
    __shared__ __align__(16) char ctx[2][NT * FDIM * 2];   // 2 x 12 KB
    __shared__ float spart[2][4][16];     // [buf][wave][row]
    __shared__ const char* rowp[3 * NPAD];
    __shared__ float code_s[DIM];
    __shared__ float red[2][DIM];

    const int b    = blockIdx.x;
    const int tid  = threadIdx.x;
    const int wave = tid >> 6;        // = d-quarter
    const int lane = tid & 63;
    const int c    = lane & 15;       // MFMA col-within-16
    const int g    = lane >> 4;       // k-slot / row-group

    // ---- per-block: precompute gather row pointers (padded to 256) ----
    const int* xs_b = xs_xt + b * (N_TOT * 2);
    const int* p_b  = path_idx + b * N_TOT;
    for (int i = tid; i < 3 * NPAD; i += THREADS) {
        int seg = i >> 8, n = i & (NPAD - 1);
        int m = n < N_TOT ? n : N_TOT - 1;
        const char* base;
        if      (seg == 0) base = (const char*)(value_vocab + (size_t)xs_b[2 * m]     * DIM);
        else if (seg == 1) base = (const char*)(path_vocab  + (size_t)p_b[m]          * DIM);
        else               base = (const char*)(value_vocab + (size_t)xs_b[2 * m + 1] * DIM);
        rowp[i] = base;
    }
    __syncthreads();

    // ---- staging invariants: 1536 dwordx4 units/tile, 6/thread, coalesced ----
    int ridx[6], ldsb[6];
    const int boff = (tid & 31) * 16;              // p-independent (256p % 32 == 0... 256p>>5 changes s only)
    #pragma unroll
    for (int p = 0; p < 6; ++p) {
        int u   = tid + THREADS * p;      // 0..1535
        int s   = u >> 5;                 // segment-row 0..47
        int seg = s >> 4, nl = s & 15;
        ridx[p] = seg * NPAD + nl;
        int f  = seg * 128 + (u & 31) * 4;
        int ks = f >> 5, gg = (f >> 3) & 3, hh = (f >> 2) & 1;
        ldsb[p] = ks * 1024 + ((nl * 64 + gg * 16) ^ ((ks & 1) << 6)) + hh * 8;
    }

    auto stage_issue = [&](int t, float4* pf) {
        #pragma unroll
        for (int p = 0; p < 6; ++p) {
            const char* rp = rowp[ridx[p] + t * NT];
            pf[p] = *(const float4*)(rp + boff);
        }
    };
    auto stage_write = [&](char* base, const float4* pf) {
        #pragma unroll
        for (int p = 0; p < 6; ++p) {
            float4 v = pf[p];
            *(uint2*)(base + ldsb[p]) = make_uint2(pk2(v.x, v.y), pk2(v.z, v.w));
        }
    };

    float4 pfA[6];

    // ---- prologue: W slice (32 d) fully register-resident ----
    stage_issue(0, pfA);
    short8 wf0[KSTEPS], wf1[KSTEPS];
    {
        const char* wb = (const char*)wsB;
        const int ds0 = 2 * wave, ds1 = 2 * wave + 1;
        #pragma unroll
        for (int ks = 0; ks < KSTEPS; ++ks) {
            wf0[ks] = *(const short8*)(wb + ((ds0 * KSTEPS + ks) * 64 + lane) * 16);
            wf1[ks] = *(const short8*)(wb + ((ds1 * KSTEPS + ks) * 64 + lane) * 16);
        }
    }
    const float a0v = att_vec[32 * wave + c];
    const float a1v = att_vec[32 * wave + 16 + c];

    stage_write(ctx[0], pfA);     // waits pfA (tile 0)
    stage_issue(1, pfA);          // tile 1 in flight
    __syncthreads();              // tile 0 visible

    float P0 = 0.f, P1 = 0.f, L = 0.f;
    float comb0[4], comb1[4];
    const int ab = c * 64 + g * 16;

    auto do_tile = [&](int t) {
        const char* cb = ctx[t & 1];
        f32x4 acc0 = {0.f, 0.f, 0.f, 0.f};
        f32x4 acc1 = {0.f, 0.f, 0.f, 0.f};
        #pragma unroll
        for (int ks = 0; ks < KSTEPS; ++ks) {
            short8 a = *(const short8*)(cb + ks * 1024 + (ab ^ ((ks & 1) << 6)));
            acc0 = __builtin_amdgcn_mfma_f32_16x16x32_bf16(a, wf0[ks], acc0, 0, 0, 0);
            acc1 = __builtin_amdgcn_mfma_f32_16x16x32_bf16(a, wf1[ks], acc1, 0, 0, 0);
        }
        float sp[4];
        #pragma unroll
        for (int r = 0; r < 4; ++r) {
            comb0[r] = fast_tanh(acc0[r]);
            comb1[r] = fast_tanh(acc1[r]);
            sp[r] = fmaf(comb0[r], a0v, comb1[r] * a1v);
        }
        #pragma unroll
        for (int r = 0; r < 4; ++r) sp[r] = dpp_red16(sp[r]);   // sum over 16 c (VALU)
        if (c == 0) {   // lanes 0,16,32,48: one float4 per row-quad
            *(float4*)&spart[t & 1][wave][4 * g] = make_float4(sp[0], sp[1], sp[2], sp[3]);
        }
    };
    auto finish_tile = [&](int t) {
        f32x4 q0 = *(const f32x4*)&spart[t & 1][0][4 * g];   // broadcast reads
        f32x4 q1 = *(const f32x4*)&spart[t & 1][1][4 * g];
        f32x4 q2 = *(const f32x4*)&spart[t & 1][2][4 * g];
        f32x4 q3 = *(const f32x4*)&spart[t & 1][3][4 * g];
        #pragma unroll
        for (int r = 0; r < 4; ++r) {
            float s = (q0[r] + q1[r]) + (q2[r] + q3[r]);
            float e = (t * NT + 4 * g + r < N_TOT) ? __expf(s) : 0.f;  // |s|<=~5
            L += e;
            P0 = fmaf(e, comb0[r], P0);
            P1 = fmaf(e, comb1[r], P1);
        }
    };

    #pragma unroll 1
    for (int t = 0; t < NTILES; ++t) {
        if (t + 1 < NTILES) {
            stage_write(ctx[(t + 1) & 1], pfA);     // tile t+1 (issued at t-1)
            if (t + 2 < NTILES) stage_issue(t + 2, pfA);
        }
        do_tile(t);
        __syncthreads();   // spart[t&1] ready AND ctx[(t+1)&1] visible
        finish_tile(t);
    }

    // ---- reduce over g (row-quads); code = P/L ----
    P0 += __shfl_xor(P0, 16, 64);
    P0 += __shfl_xor(P0, 32, 64);
    P1 += __shfl_xor(P1, 16, 64);
    P1 += __shfl_xor(P1, 32, 64);
    L  += __shfl_xor(L, 16, 64);
    L  += __shfl_xor(L, 32, 64);
    if (lane < 16) {
        code_s[32 * wave + c]      = P0 / L;
        code_s[32 * wave + 16 + c] = P1 / L;
    }
    __syncthreads();

    // ---- dense + sigmoid ----
    const int o  = tid & 127;
    const int sg = tid >> 7;
    float partial = 0.f;
    #pragma unroll 8
    for (int d = 64 * sg; d < 64 * sg + 64; ++d)
        partial = fmaf(code_s[d], dense_w[d * DIM + o], partial);
    red[sg][o] = partial;
    __syncthreads();
    if (tid < DIM) {
        float a2 = dense_b[tid] + red[0][tid] + red[1][tid];
        out[(size_t)b * DIM + tid] = 1.f / (1.f + __expf(-a2));
    }
}

extern "C" void kernel_launch(void* const* d_in, const int* in_sizes, int n_in,
                              void* d_out, int out_size, void* d_ws, size_t ws_size,
                              hipStream_t stream) {
    const int*   xs_xt       = (const int*)d_in[0];
    const int*   path_idx    = (const int*)d_in[1];
    const float* value_vocab = (const float*)d_in[2];
    const float* path_vocab  = (const float*)d_in[3];
    const float* W           = (const float*)d_in[4];
    const float* att_vec     = (const float*)d_in[5];
    const float* dense_w     = (const float*)d_in[6];
    const float* dense_b     = (const float*)d_in[7];
    float*       out         = (float*)d_out;

    unsigned* wsB = (unsigned*)d_ws;    // 24576 uints = 96 KB

    prep_w<<<96, 256, 0, stream>>>(W, wsB);
    acv_kernel<<<1024, THREADS, 0, stream>>>(xs_xt, path_idx, value_vocab, path_vocab,
                                             wsB, att_vec, dense_w, dense_b, out);
}